// Round 3
// baseline (456.473 us; speedup 1.0000x reference)
//
#include <hip/hip_runtime.h>
#include <hip/hip_cooperative_groups.h>
#include <math.h>

namespace cg = cooperative_groups;

#define M 256
#define D 768
#define D4 (D/4)          // 192
#define THRESH 0.3
#define EPS 1e-8
#define NBLK 512          // 2 blocks/CU on 256 CUs — cooperative co-residency guaranteed

typedef float vfloat4 __attribute__((ext_vector_type(4)));

// Workspace layout (floats):
#define WS_SM    0      // [256] row sums of mem
#define WS_NM2   256    // [256] row sumsq
#define WS_KX    512    // [256] dot(mem_i, x)
#define WS_MASK  768    // [256] mask
#define WS_SX    1024
#define WS_NX2   1025
#define WS_MEMT  2048                 // [D*M] mem transposed, float4-chunked
#define WS_ST    (2048 + D * M)       // [M*M] sT[i*M + a] = s[a,i]

__global__ __launch_bounds__(256, 2) void fused(const float* __restrict__ x,
                                                const float* __restrict__ mem,
                                                const float* __restrict__ noise,
                                                float* __restrict__ ws,
                                                float* __restrict__ out) {
    const int b = blockIdx.x;
    const int t = threadIdx.x;
    cg::grid_group grid = cg::this_grid();

    __shared__ double sh0[256], sh1[256], sh2[256];
    __shared__ vfloat4 lrow4[D4];
    __shared__ float shc[M], sha[M], shr[M];
    __shared__ float ssh[8][16];
    __shared__ float shm[8];

    // ================= phase 1: per-row stats + chunked transpose =================
    if (b <= M) {
        const float* row = (b < M) ? (mem + (size_t)b * D) : x;
        double s = 0.0, sq = 0.0, dt = 0.0;
        for (int d = t; d < D; d += 256) {
            float mf = row[d];
            double m = (double)mf;
            double xv = (double)x[d];
            s += m; sq += m * m; dt += m * xv;
            if (b < M) ws[WS_MEMT + (d >> 2) * (M * 4) + b * 4 + (d & 3)] = mf;
        }
        sh0[t] = s; sh1[t] = sq; sh2[t] = dt;
        __syncthreads();
        for (int k = 128; k > 0; k >>= 1) {
            if (t < k) { sh0[t] += sh0[t + k]; sh1[t] += sh1[t + k]; sh2[t] += sh2[t + k]; }
            __syncthreads();
        }
        if (t == 0) {
            if (b < M) {
                ws[WS_SM + b]  = (float)sh0[0];
                ws[WS_NM2 + b] = (float)sh1[0];
                ws[WS_KX + b]  = (float)sh2[0];
            } else {
                ws[WS_SX]  = (float)sh0[0];
                ws[WS_NX2] = (float)sh1[0];
            }
        }
    }
    grid.sync();

    // ================= phase 2: mask + Gram row + reductions + s[a,i] =================
    if (b < M) {
        const int i = b;
        const int a = t;

        const double nxd   = fmax(sqrt(fmax((double)ws[WS_NX2], 0.0)), EPS);
        const double nm2ad = (double)ws[WS_NM2 + a];
        const double nmsad = fmax(sqrt(fmax(nm2ad, 0.0)), EPS);
        const double mxad  = (double)ws[WS_KX + a] / (nmsad * nxd);
        const float maska = (mxad > THRESH) ? 1.0f : 0.0f;
        const float nmsa  = (float)nmsad;
        if (i == 0) ws[WS_MASK + a] = maska;

        if (a < D4) lrow4[a] = ((const vfloat4*)mem)[(size_t)i * D4 + a];
        __syncthreads();

        const vfloat4* memT4 = (const vfloat4*)(ws + WS_MEMT);
        float acc0 = 0.f, acc1 = 0.f, acc2 = 0.f, acc3 = 0.f;
        for (int dq = 0; dq < D4; dq += 4) {
            vfloat4 v0 = memT4[(dq + 0) * M + a]; vfloat4 l0 = lrow4[dq + 0];
            vfloat4 v1 = memT4[(dq + 1) * M + a]; vfloat4 l1 = lrow4[dq + 1];
            vfloat4 v2 = memT4[(dq + 2) * M + a]; vfloat4 l2 = lrow4[dq + 2];
            vfloat4 v3 = memT4[(dq + 3) * M + a]; vfloat4 l3 = lrow4[dq + 3];
            acc0 += v0.x * l0.x + v0.y * l0.y + v0.z * l0.z + v0.w * l0.w;
            acc1 += v1.x * l1.x + v1.y * l1.y + v1.z * l1.z + v1.w * l1.w;
            acc2 += v2.x * l2.x + v2.y * l2.y + v2.z * l2.z + v2.w * l2.w;
            acc3 += v3.x * l3.x + v3.y * l3.y + v3.z * l3.z + v3.w * l3.w;
        }
        const float g = (acc0 + acc1) + (acc2 + acc3);

        shc[a] = maska;
        sha[a] = maska * ws[WS_SM + a] / nmsa;
        shr[a] = (maska / nmsa) * g;
        __syncthreads();
        for (int k = 128; k > 0; k >>= 1) {
            if (a < k) { shc[a] += shc[a + k]; sha[a] += sha[a + k]; shr[a] += shr[a + k]; }
            __syncthreads();
        }
        const float cnt = shc[0];
        const float A2  = sha[0];
        const float A1  = shr[0];

        const float nm2i = ws[WS_NM2 + i];
        const float Smi  = ws[WS_SM + i];
        const float kxi  = ws[WS_KX + i];
        const float nmsi = fmaxf(sqrtf(fmaxf(nm2i, 0.f)), 1e-8f);
        const float nx   = (float)nxd;
        const float Sx   = ws[WS_SX];
        const float mxi  = kxi / (nmsi * nx);

        const float c = g / (nmsa * nmsi) + mxi;
        const float nkp = sqrtf(fmaxf(nm2i + 2.f * c * Smi + (float)D * c * c, 1e-16f));
        const float cos_kp_x = (kxi + c * Sx) / (nkp * nx);
        const float mean_cos_km = (cnt > 0.f) ? (A1 + c * A2) / (nkp * fmaxf(cnt, 1.f)) : 0.f;

        ws[WS_ST + i * M + a] = c + cos_kp_x + mean_cos_km;
    }
    grid.sync();

    // ================= phase 3: stream the full output in one pass =================
    // unit u = a*16 + islab : 16 rows x 192 float4 = 48 KB contiguous. 4096 units,
    // 8 per block. Active: mem + s + noise. Inactive: NT zero-store (fill pattern).
    {
        const int u0 = b * 8;
        if (t < 128) {
            const int j  = t >> 4;
            const int il = t & 15;
            const int u  = u0 + j;
            const int a  = u >> 4;
            const int i0 = (u & 15) << 4;
            ssh[j][il] = ws[WS_ST + (i0 + il) * M + a];
        }
        if (t < 8) shm[t] = ws[WS_MASK + ((u0 + t) >> 4)];
        __syncthreads();

        vfloat4* out4         = (vfloat4*)out;
        const vfloat4* noise4 = (const vfloat4*)noise;
        const vfloat4* mem4   = (const vfloat4*)mem;

        for (int j = 0; j < 8; ++j) {
            const int u  = u0 + j;
            const int a  = u >> 4;
            const int i0 = (u & 15) << 4;
            const size_t ob = ((size_t)a * M + i0) * D4;   // float4 index base
            if (shm[j] == 0.0f) {
                const vfloat4 z = (vfloat4){0.f, 0.f, 0.f, 0.f};
                #pragma unroll
                for (int k = 0; k < 12; ++k)
                    __builtin_nontemporal_store(z, out4 + ob + t + k * 256);
            } else {
                const size_t mb = (size_t)i0 * D4;
                #pragma unroll
                for (int k = 0; k < 12; ++k) {
                    const int f = t + k * 256;
                    vfloat4 n = __builtin_nontemporal_load(noise4 + ob + f);
                    vfloat4 m = mem4[mb + f];
                    const float s = ssh[j][f / 192];
                    vfloat4 o;
                    o.x = m.x + s + n.x;
                    o.y = m.y + s + n.y;
                    o.z = m.z + s + n.z;
                    o.w = m.w + s + n.w;
                    __builtin_nontemporal_store(o, out4 + ob + f);
                }
            }
        }
    }
}

extern "C" void kernel_launch(void* const* d_in, const int* in_sizes, int n_in,
                              void* d_out, int out_size, void* d_ws, size_t ws_size,
                              hipStream_t stream) {
    const float* x     = (const float*)d_in[0];   // [1, D]
    const float* mem   = (const float*)d_in[1];   // [M, D]
    const float* noise = (const float*)d_in[2];   // [M, M, D]
    float* out = (float*)d_out;
    float* ws  = (float*)d_ws;

    void* args[] = {(void*)&x, (void*)&mem, (void*)&noise, (void*)&ws, (void*)&out};
    hipLaunchCooperativeKernel((void*)fused, dim3(NBLK), dim3(256), args, 0, stream);
}

// Round 4
// 380.131 us; speedup vs baseline: 1.2008x; 1.2008x over previous
//
#include <hip/hip_runtime.h>
#include <hip/hip_cooperative_groups.h>
#include <math.h>

namespace cg = cooperative_groups;

#define M 256
#define D 768
#define D4 (D/4)          // 192
#define THRESH 0.3
#define EPS 1e-8

typedef float vfloat4 __attribute__((ext_vector_type(4)));

// Workspace layout (floats):
#define WS_SM    0      // [256] row sums of mem
#define WS_NM2   256    // [256] row sumsq
#define WS_KX    512    // [256] dot(mem_i, x)
#define WS_MASK  768    // [256] mask
#define WS_SX    1024
#define WS_NX2   1025
#define WS_MEMT  2048                 // [D*M] mem transposed, float4-chunked:
                                      // element (d,r) at (d>>2)*1024 + r*4 + (d&3)
#define WS_ST    (2048 + D * M)       // [M*M] sT[i*M + a] = s[a,i]

// ---- Kernel A (cooperative, 256 blocks x 512 threads = 8 waves/CU):
// phase 1: per-row stats (double) + chunked transpose; block 0 also x stats.
// grid.sync()
// phase 2: mask (double) + Gram row (split over 2 thread-halves) + reductions + s[a,i].
__global__ __launch_bounds__(512) void kA(const float* __restrict__ x,
                                          const float* __restrict__ mem,
                                          float* __restrict__ ws) {
    const int b = blockIdx.x;   // 0..255
    const int t = threadIdx.x;  // 0..511
    cg::grid_group grid = cg::this_grid();

    __shared__ double sh0[512], sh1[512], sh2[512];

    // ================= phase 1: stats + transpose =================
    {
        const float* row = mem + (size_t)b * D;
        double s = 0.0, sq = 0.0, dt = 0.0;
        for (int d = t; d < D; d += 512) {
            float mf = row[d];
            double m = (double)mf;
            double xv = (double)x[d];
            s += m; sq += m * m; dt += m * xv;
            ws[WS_MEMT + (d >> 2) * (M * 4) + b * 4 + (d & 3)] = mf;
        }
        sh0[t] = s; sh1[t] = sq; sh2[t] = dt;
        __syncthreads();
        for (int k = 256; k > 0; k >>= 1) {
            if (t < k) { sh0[t] += sh0[t + k]; sh1[t] += sh1[t + k]; sh2[t] += sh2[t + k]; }
            __syncthreads();
        }
        if (t == 0) {
            ws[WS_SM + b]  = (float)sh0[0];
            ws[WS_NM2 + b] = (float)sh1[0];
            ws[WS_KX + b]  = (float)sh2[0];
        }
        if (b == 0) {   // x stats
            __syncthreads();
            double s2 = 0.0, sq2 = 0.0;
            for (int d = t; d < D; d += 512) {
                double xv = (double)x[d];
                s2 += xv; sq2 += xv * xv;
            }
            sh0[t] = s2; sh1[t] = sq2;
            __syncthreads();
            for (int k = 256; k > 0; k >>= 1) {
                if (t < k) { sh0[t] += sh0[t + k]; sh1[t] += sh1[t + k]; }
                __syncthreads();
            }
            if (t == 0) {
                ws[WS_SX]  = (float)sh0[0];
                ws[WS_NX2] = (float)sh1[0];
            }
        }
    }
    grid.sync();

    // ================= phase 2: mask + Gram + reductions + s =================
    {
        const int i = b;
        const int a = t & 255;
        const int h = t >> 8;   // which half of the dq range this thread covers

        // mask in double (threshold crossing must match reference exactly)
        const double nxd   = fmax(sqrt(fmax((double)ws[WS_NX2], 0.0)), EPS);
        const double nm2ad = (double)ws[WS_NM2 + a];
        const double nmsad = fmax(sqrt(fmax(nm2ad, 0.0)), EPS);
        const double mxad  = (double)ws[WS_KX + a] / (nmsad * nxd);
        const float maska = (mxad > THRESH) ? 1.0f : 0.0f;
        const float nmsa  = (float)nmsad;
        if (i == 0 && h == 0) ws[WS_MASK + a] = maska;

        __shared__ vfloat4 lrow4[D4];
        if (t < D4) lrow4[t] = ((const vfloat4*)mem)[(size_t)i * D4 + t];
        __syncthreads();

        // partial Gram: half h covers dq in [h*96, h*96+96)
        const vfloat4* memT4 = (const vfloat4*)(ws + WS_MEMT);
        float acc0 = 0.f, acc1 = 0.f, acc2 = 0.f, acc3 = 0.f;
        const int dq0 = h * 96;
        for (int dq = dq0; dq < dq0 + 96; dq += 4) {
            vfloat4 v0 = memT4[(dq + 0) * M + a]; vfloat4 l0 = lrow4[dq + 0];
            vfloat4 v1 = memT4[(dq + 1) * M + a]; vfloat4 l1 = lrow4[dq + 1];
            vfloat4 v2 = memT4[(dq + 2) * M + a]; vfloat4 l2 = lrow4[dq + 2];
            vfloat4 v3 = memT4[(dq + 3) * M + a]; vfloat4 l3 = lrow4[dq + 3];
            acc0 += v0.x * l0.x + v0.y * l0.y + v0.z * l0.z + v0.w * l0.w;
            acc1 += v1.x * l1.x + v1.y * l1.y + v1.z * l1.z + v1.w * l1.w;
            acc2 += v2.x * l2.x + v2.y * l2.y + v2.z * l2.z + v2.w * l2.w;
            acc3 += v3.x * l3.x + v3.y * l3.y + v3.z * l3.z + v3.w * l3.w;
        }
        __shared__ float shg[512];
        shg[t] = (acc0 + acc1) + (acc2 + acc3);
        __syncthreads();
        const float g = shg[a] + shg[a + 256];

        // float reductions: cnt, A2, A1[i] = sum_a (mask_a/nms_a) * g[a]
        __shared__ float shc[M], sha[M], shr[M];
        if (h == 0) {
            shc[a] = maska;
            sha[a] = maska * ws[WS_SM + a] / nmsa;
            shr[a] = (maska / nmsa) * g;
        }
        __syncthreads();
        for (int k = 128; k > 0; k >>= 1) {
            if (t < k) { shc[t] += shc[t + k]; sha[t] += sha[t + k]; shr[t] += shr[t + k]; }
            __syncthreads();
        }

        if (h == 0) {
            const float cnt = shc[0];
            const float A2  = sha[0];
            const float A1  = shr[0];

            const float nm2i = ws[WS_NM2 + i];
            const float Smi  = ws[WS_SM + i];
            const float kxi  = ws[WS_KX + i];
            const float nmsi = fmaxf(sqrtf(fmaxf(nm2i, 0.f)), 1e-8f);
            const float nx   = (float)nxd;
            const float Sx   = ws[WS_SX];
            const float mxi  = kxi / (nmsi * nx);

            const float c = g / (nmsa * nmsi) + mxi;
            const float nkp = sqrtf(fmaxf(nm2i + 2.f * c * Smi + (float)D * c * c, 1e-16f));
            const float cos_kp_x = (kxi + c * Sx) / (nkp * nx);
            const float mean_cos_km = (cnt > 0.f) ? (A1 + c * A2) / (nkp * fmaxf(cnt, 1.f)) : 0.f;

            ws[WS_ST + i * M + a] = c + cos_kp_x + mean_cos_km;
        }
    }
}

// ---- Kernel B: single streaming pass over the whole output (high occupancy).
// Active rows: out[a,i,:] = mem[i,:] + s[a,i] + noise[a,i,:].
// Inactive rows: contiguous NT zero-store.
// grid (16, 256) x 192 threads  (~30 waves/CU resident).
__global__ __launch_bounds__(D4) void kB(const float* __restrict__ mem,
                                         const float* __restrict__ noise,
                                         const float* __restrict__ ws,
                                         float* __restrict__ out) {
    const int a  = blockIdx.y;
    const int i0 = blockIdx.x * 16;
    const int t  = threadIdx.x;   // 0..191

    vfloat4* out4 = (vfloat4*)out;
    const size_t base = ((size_t)a * M + i0) * D4 + t;

    if (ws[WS_MASK + a] == 0.0f) {
        const vfloat4 z = (vfloat4){0.f, 0.f, 0.f, 0.f};
        #pragma unroll
        for (int il = 0; il < 16; ++il)
            __builtin_nontemporal_store(z, out4 + base + (size_t)il * D4);
        return;
    }

    const vfloat4* mem4   = (const vfloat4*)mem;
    const vfloat4* noise4 = (const vfloat4*)noise;

    __shared__ float ssh[16];
    if (t < 16) ssh[t] = ws[WS_ST + (i0 + t) * M + a];
    __syncthreads();

    #pragma unroll 4
    for (int il = 0; il < 16; ++il) {
        const float s = ssh[il];
        vfloat4 m = mem4[(size_t)(i0 + il) * D4 + t];
        vfloat4 n = noise4[base + (size_t)il * D4];   // plain load: let L2/L3 cache noise
        vfloat4 o;
        o.x = m.x + s + n.x;
        o.y = m.y + s + n.y;
        o.z = m.z + s + n.z;
        o.w = m.w + s + n.w;
        __builtin_nontemporal_store(o, out4 + base + (size_t)il * D4);
    }
}

extern "C" void kernel_launch(void* const* d_in, const int* in_sizes, int n_in,
                              void* d_out, int out_size, void* d_ws, size_t ws_size,
                              hipStream_t stream) {
    const float* x     = (const float*)d_in[0];   // [1, D]
    const float* mem   = (const float*)d_in[1];   // [M, D]
    const float* noise = (const float*)d_in[2];   // [M, M, D]
    float* out = (float*)d_out;
    float* ws  = (float*)d_ws;

    void* argsA[] = {(void*)&x, (void*)&mem, (void*)&ws};
    hipLaunchCooperativeKernel((void*)kA, dim3(M), dim3(512), argsA, 0, stream);
    kB<<<dim3(16, M), dim3(D4), 0, stream>>>(mem, noise, ws, out);
}

// Round 5
// 335.120 us; speedup vs baseline: 1.3621x; 1.1343x over previous
//
#include <hip/hip_runtime.h>
#include <math.h>

#define M 256
#define D 768
#define D4 (D/4)          // 192
#define THRESH 0.3
#define EPS 1e-8
#define ZFB 4096          // zero-fill blocks in k2 (one per (a, i-slab16) unit)

typedef float vfloat4 __attribute__((ext_vector_type(4)));

// Workspace layout (floats):
#define WS_SM    0      // [256] row sums of mem
#define WS_NM2   256    // [256] row sumsq
#define WS_KX    512    // [256] dot(mem_i, x)
#define WS_MASK  768    // [256] mask (written by k1)
#define WS_SX    1024
#define WS_NX2   1025
#define WS_MEMT  2048                 // [D*M] mem transposed, float4-chunked:
                                      // element (d,r) at (d>>2)*1024 + r*4 + (d&3)
#define WS_ST    (2048 + D * M)       // [M*M] sT[i*M + a] = s[a,i]

// ---- K1: block r — row-r stats + chunked transpose + redundant x-stats + mask_r.
// x-stats are accumulated with the same stride-256 pattern and tree reduction in
// every block -> bitwise identical across blocks; block 0 publishes them.
__global__ __launch_bounds__(256) void k1_stats(const float* __restrict__ x,
                                                const float* __restrict__ mem,
                                                float* __restrict__ ws) {
    const int r = blockIdx.x;
    const int t = threadIdx.x;
    const float* row = mem + (size_t)r * D;

    double s = 0.0, sq = 0.0, dt = 0.0, xs = 0.0, xq = 0.0;
    for (int d = t; d < D; d += 256) {
        float mf = row[d];
        double m  = (double)mf;
        double xv = (double)x[d];
        s += m; sq += m * m; dt += m * xv;
        xs += xv; xq += xv * xv;
        ws[WS_MEMT + (d >> 2) * (M * 4) + r * 4 + (d & 3)] = mf;
    }
    __shared__ double sh0[256], sh1[256], sh2[256], sh3[256], sh4[256];
    sh0[t] = s; sh1[t] = sq; sh2[t] = dt; sh3[t] = xs; sh4[t] = xq;
    __syncthreads();
    for (int k = 128; k > 0; k >>= 1) {
        if (t < k) {
            sh0[t] += sh0[t + k]; sh1[t] += sh1[t + k]; sh2[t] += sh2[t + k];
            sh3[t] += sh3[t + k]; sh4[t] += sh4[t + k];
        }
        __syncthreads();
    }
    if (t == 0) {
        const float smf  = (float)sh0[0];
        const float nm2f = (float)sh1[0];
        const float kxf  = (float)sh2[0];
        const float sxf  = (float)sh3[0];
        const float nx2f = (float)sh4[0];
        ws[WS_SM + r]  = smf;
        ws[WS_NM2 + r] = nm2f;
        ws[WS_KX + r]  = kxf;
        if (r == 0) { ws[WS_SX] = sxf; ws[WS_NX2] = nx2f; }
        // mask in double on float-rounded stats — identical to prior passing rounds
        const double nxd  = fmax(sqrt(fmax((double)nx2f, 0.0)), EPS);
        const double nmsd = fmax(sqrt(fmax((double)nm2f, 0.0)), EPS);
        const double mxd  = (double)kxf / (nmsd * nxd);
        ws[WS_MASK + r] = (mxd > THRESH) ? 1.0f : 0.0f;
    }
}

// ---- K2: one dispatch, two roles.
// blocks 0..255   : Gram row i + reductions + s[a,i]   (L2-bound)
// blocks 256..+ZFB: zero-fill inactive output rows      (HBM writes, overlaps Gram)
__global__ __launch_bounds__(256) void k2_gram_zfill(const float* __restrict__ mem,
                                                     float* __restrict__ ws,
                                                     float* __restrict__ out) {
    const int bid = blockIdx.x;
    const int t   = threadIdx.x;

    if (bid >= M) {
        // ---- zero-fill role: unit u = (a, 16-row i-slab) ----
        const int u = bid - M;
        const int a = u >> 4;
        if (ws[WS_MASK + a] != 0.0f) return;
        const int i0 = (u & 15) << 4;
        vfloat4* out4 = (vfloat4*)out;
        const size_t base = ((size_t)a * M + i0) * D4;   // 3072 float4 = 48 KB
        const vfloat4 z = (vfloat4){0.f, 0.f, 0.f, 0.f};
        #pragma unroll
        for (int k = 0; k < 12; ++k)
            __builtin_nontemporal_store(z, out4 + base + t + k * 256);
        return;
    }

    // ---- Gram role: block i ----
    const int i = bid;
    const int a = t;

    const float maska = ws[WS_MASK + a];
    const double nmsad = fmax(sqrt(fmax((double)ws[WS_NM2 + a], 0.0)), EPS);
    const float  nmsa  = (float)nmsad;

    __shared__ vfloat4 lrow4[D4];
    if (a < D4) lrow4[a] = ((const vfloat4*)mem)[(size_t)i * D4 + a];
    __syncthreads();

    // g[a] = dot(mem_i, mem_a) via chunked-transposed memT (coalesced float4 L2 loads)
    const vfloat4* memT4 = (const vfloat4*)(ws + WS_MEMT);
    float acc0 = 0.f, acc1 = 0.f, acc2 = 0.f, acc3 = 0.f;
    for (int dq = 0; dq < D4; dq += 4) {
        vfloat4 v0 = memT4[(dq + 0) * M + a]; vfloat4 l0 = lrow4[dq + 0];
        vfloat4 v1 = memT4[(dq + 1) * M + a]; vfloat4 l1 = lrow4[dq + 1];
        vfloat4 v2 = memT4[(dq + 2) * M + a]; vfloat4 l2 = lrow4[dq + 2];
        vfloat4 v3 = memT4[(dq + 3) * M + a]; vfloat4 l3 = lrow4[dq + 3];
        acc0 += v0.x * l0.x + v0.y * l0.y + v0.z * l0.z + v0.w * l0.w;
        acc1 += v1.x * l1.x + v1.y * l1.y + v1.z * l1.z + v1.w * l1.w;
        acc2 += v2.x * l2.x + v2.y * l2.y + v2.z * l2.z + v2.w * l2.w;
        acc3 += v3.x * l3.x + v3.y * l3.y + v3.z * l3.z + v3.w * l3.w;
    }
    const float g = (acc0 + acc1) + (acc2 + acc3);

    // float reductions: cnt, A2, A1[i] = sum_a (mask_a/nms_a) * g[a]
    __shared__ float shc[M], sha[M], shr[M];
    shc[a] = maska;
    sha[a] = maska * ws[WS_SM + a] / nmsa;
    shr[a] = (maska / nmsa) * g;
    __syncthreads();
    for (int k = 128; k > 0; k >>= 1) {
        if (a < k) { shc[a] += shc[a + k]; sha[a] += sha[a + k]; shr[a] += shr[a + k]; }
        __syncthreads();
    }
    const float cnt = shc[0];
    const float A2  = sha[0];
    const float A1  = shr[0];

    // i-uniform stats (float — output tolerance is generous)
    const float nm2i = ws[WS_NM2 + i];
    const float Smi  = ws[WS_SM + i];
    const float kxi  = ws[WS_KX + i];
    const float nmsi = fmaxf(sqrtf(fmaxf(nm2i, 0.f)), 1e-8f);
    const float nx   = fmaxf(sqrtf(fmaxf(ws[WS_NX2], 0.f)), 1e-8f);
    const float Sx   = ws[WS_SX];
    const float mxi  = kxi / (nmsi * nx);

    const float c = g / (nmsa * nmsi) + mxi;
    const float nkp = sqrtf(fmaxf(nm2i + 2.f * c * Smi + (float)D * c * c, 1e-16f));
    const float cos_kp_x = (kxi + c * Sx) / (nkp * nx);
    const float mean_cos_km = (cnt > 0.f) ? (A1 + c * A2) / (nkp * fmaxf(cnt, 1.f)) : 0.f;

    ws[WS_ST + i * M + a] = c + cos_kp_x + mean_cos_km;
}

// ---- K3: active rows only — out[a,i,:] = mem[i,:] + s[a,i] + noise[a,i,:] ----
// grid (16, 256) x 192 threads (~48 waves/CU demand — streaming needs the TLP).
__global__ __launch_bounds__(D4) void k3_stream(const float* __restrict__ mem,
                                                const float* __restrict__ noise,
                                                const float* __restrict__ ws,
                                                float* __restrict__ out) {
    const int a = blockIdx.y;
    if (ws[WS_MASK + a] == 0.0f) return;   // zero-fill handled in k2
    const int i0 = blockIdx.x * 16;
    const int t  = threadIdx.x;   // 0..191

    const vfloat4* mem4   = (const vfloat4*)mem;
    const vfloat4* noise4 = (const vfloat4*)noise;
    vfloat4* out4         = (vfloat4*)out;
    const size_t base = ((size_t)a * M + i0) * D4 + t;

    __shared__ float ssh[16];
    if (t < 16) ssh[t] = ws[WS_ST + (i0 + t) * M + a];
    __syncthreads();

    #pragma unroll 4
    for (int il = 0; il < 16; ++il) {
        const float s = ssh[il];
        vfloat4 m = mem4[(size_t)(i0 + il) * D4 + t];
        vfloat4 n = noise4[base + (size_t)il * D4];   // plain load: L2/L3-friendly
        vfloat4 o;
        o.x = m.x + s + n.x;
        o.y = m.y + s + n.y;
        o.z = m.z + s + n.z;
        o.w = m.w + s + n.w;
        __builtin_nontemporal_store(o, out4 + base + (size_t)il * D4);
    }
}

extern "C" void kernel_launch(void* const* d_in, const int* in_sizes, int n_in,
                              void* d_out, int out_size, void* d_ws, size_t ws_size,
                              hipStream_t stream) {
    const float* x     = (const float*)d_in[0];   // [1, D]
    const float* mem   = (const float*)d_in[1];   // [M, D]
    const float* noise = (const float*)d_in[2];   // [M, M, D]
    float* out = (float*)d_out;
    float* ws  = (float*)d_ws;

    k1_stats<<<dim3(M), dim3(256), 0, stream>>>(x, mem, ws);
    k2_gram_zfill<<<dim3(M + ZFB), dim3(256), 0, stream>>>(mem, ws, out);
    k3_stream<<<dim3(16, M), dim3(D4), 0, stream>>>(mem, noise, ws, out);
}